// Round 12
// baseline (59.256 us; speedup 1.0000x reference)
//
#include <hip/hip_runtime.h>
#include <hip/hip_bf16.h>

typedef __bf16 bf16x8 __attribute__((ext_vector_type(8)));
typedef __bf16 bf16x4 __attribute__((ext_vector_type(4)));
typedef float  f32x4  __attribute__((ext_vector_type(4)));

constexpr int kD  = 512;
constexpr int kBD = 64;
constexpr int kN  = 4096;
constexpr int kB  = 8;

__device__ __forceinline__ bf16x8 cvt8v(f32x4 a, f32x4 b) {
    bf16x8 r;
    r[0] = (__bf16)a[0]; r[1] = (__bf16)a[1]; r[2] = (__bf16)a[2]; r[3] = (__bf16)a[3];
    r[4] = (__bf16)b[0]; r[5] = (__bf16)b[1]; r[6] = (__bf16)b[2]; r[7] = (__bf16)b[3];
    return r;
}
__device__ __forceinline__ bf16x8 cvt8(float4 a, float4 b) {
    bf16x8 r;
    r[0] = (__bf16)a.x; r[1] = (__bf16)a.y; r[2] = (__bf16)a.z; r[3] = (__bf16)a.w;
    r[4] = (__bf16)b.x; r[5] = (__bf16)b.y; r[6] = (__bf16)b.z; r[7] = (__bf16)b.w;
    return r;
}

#define GLD2X(ra, rb, base_, off_)                                            \
    asm volatile("global_load_dwordx4 %0, %2, off offset:%c3\n\t"             \
                 "global_load_dwordx4 %1, %2, off offset:%c4"                 \
                 : "=v"(ra), "=v"(rb)                                         \
                 : "v"(base_), "i"(off_), "i"((off_) + 16));
#define WAITN2(n_, r0, r1)                                                    \
    asm volatile("s_waitcnt vmcnt(%c2)" : "+v"(r0), "+v"(r1) : "i"(n_));
#define WAITN4(n_, r0, r1, r2, r3)                                            \
    asm volatile("s_waitcnt vmcnt(%c4)"                                       \
                 : "+v"(r0), "+v"(r1), "+v"(r2), "+v"(r3) : "i"(n_));

// Prep: Wbk/Wbv fp32 -> bf16 ws images (blocks 0..31); block 32 zeroes S.
__global__ __launch_bounds__(256)
void lbm_prep(const float* __restrict__ Wbk, const float* __restrict__ Wbv,
              __bf16* __restrict__ wsk, __bf16* __restrict__ wsv,
              float* __restrict__ S)
{
    const int bid = blockIdx.x, t = threadIdx.x;
    if (bid < 32) {
        int i = (bid * 256 + t) * 4;
        float4 a = *(const float4*)(Wbk + i);
        float4 b = *(const float4*)(Wbv + i);
        bf16x4 ka, vb;
        ka[0]=(__bf16)a.x; ka[1]=(__bf16)a.y; ka[2]=(__bf16)a.z; ka[3]=(__bf16)a.w;
        vb[0]=(__bf16)b.x; vb[1]=(__bf16)b.y; vb[2]=(__bf16)b.z; vb[3]=(__bf16)b.w;
        *(bf16x4*)(wsk + i) = ka;
        *(bf16x4*)(wsv + i) = vb;
    } else {
        S[t * 2] = 0.f; S[t * 2 + 1] = 0.f;
    }
}

// Pass 1: kp[row,j] = keys[row,:].Wbk[j,:] + bbk[j]  (or values/Wbv/bbv).
// One array per block -> 64 KB LDS weights -> 2 blocks/CU -> 16 waves/CU
// (2x R11's wave count, the variable that tracks delivered BW everywhere).
// Zero-redundancy reg-path stream: each wave owns 16 private rows, 4-slot
// counted-vmcnt pipeline, 4 MFMA/step vs swizzled LDS weights, no barriers.
__global__ __launch_bounds__(512, 4)
void lbm_proj(const float* __restrict__ keys, const float* __restrict__ values,
              const __bf16* __restrict__ wsk, const __bf16* __restrict__ wsv,
              const float* __restrict__ bbk,  const float* __restrict__ bbv,
              float* __restrict__ kp,         float* __restrict__ vp)
{
    __shared__ __bf16 ldsW[kBD * kD];   // one array's weights, swizzled = 64 KB

    const int tid = threadIdx.x;
    const int w   = tid >> 6;
    const int ln  = tid & 63;
    const int l15 = ln & 15;
    const int lhi = ln >> 4;
    const int sw7 = l15 & 7;

    const int bid  = blockIdx.x;          // 512 blocks: arr x 256 row-tiles
    const int arr  = bid & 1;
    const int t0   = bid >> 1;
    const int tile = (t0 & 7) * 32 + (t0 >> 3);   // XCD-bijective (256 = 8*32)
    const int row0 = tile * 128 + w * 16;          // this wave's 16 rows

    const float*  src  = arr ? values : keys;
    const __bf16* wsrc = arr ? wsv    : wsk;
    const float*  bsrc = arr ? bbv    : bbk;
    float*        dst  = arr ? vp     : kp;

    const float* base = src + (size_t)(row0 + l15) * kD + lhi * 8;

    // prologue: 4 slots (8 loads, 8 KB/wave) in flight under weight staging
    f32x4 ra[4], rb[4];
    GLD2X(ra[0], rb[0], base,   0)
    GLD2X(ra[1], rb[1], base, 128)
    GLD2X(ra[2], rb[2], base, 256)
    GLD2X(ra[3], rb[3], base, 384)

    // stage this array's weights into swizzled LDS (once per block):
    // granule c (16B) of row j stored at c ^ (j&7) within 8-granule groups.
    #pragma unroll
    for (int i = 0; i < 8; ++i) {
        int G = i * 512 + tid;                 // granule 0..4095
        int j = G >> 6, c = G & 63;
        *(bf16x8*)&ldsW[j * kD + ((c ^ (j & 7)) << 3)] = *(const bf16x8*)(wsrc + G * 8);
    }

    float bias[4];
    #pragma unroll
    for (int jt = 0; jt < 4; ++jt) bias[jt] = bsrc[jt * 16 + l15];

    __syncthreads();   // weights resident

    f32x4 acc[4];
    #pragma unroll
    for (int jt = 0; jt < 4; ++jt) {
        acc[jt][0]=0.f; acc[jt][1]=0.f; acc[jt][2]=0.f; acc[jt][3]=0.f;
    }

    // step s: d-range [s*32, +32); slot s&3; counted vmcnt, no barriers.
#define STEP(s_, n_)                                                          \
    {                                                                         \
        WAITN2(n_, ra[(s_) & 3], rb[(s_) & 3])                                \
        bf16x8 af_ = cvt8v(ra[(s_) & 3], rb[(s_) & 3]);                       \
        if ((s_) + 4 < 16) GLD2X(ra[(s_) & 3], rb[(s_) & 3], base, ((s_) + 4) * 128) \
        const int go_ = (((s_) * 4 + lhi) ^ sw7) << 3;                        \
        _Pragma("unroll")                                                     \
        for (int jt = 0; jt < 4; ++jt) {                                      \
            bf16x8 wf_ = *(const bf16x8*)&ldsW[(jt * 16 + l15) * kD + go_];   \
            acc[jt] = __builtin_amdgcn_mfma_f32_16x16x32_bf16(af_, wf_, acc[jt], 0, 0, 0); \
        }                                                                     \
    }

    STEP(0, 6)  STEP(1, 6)  STEP(2, 6)  STEP(3, 6)
    STEP(4, 6)  STEP(5, 6)  STEP(6, 6)  STEP(7, 6)
    STEP(8, 6)  STEP(9, 6)  STEP(10, 6) STEP(11, 6)
    STEP(12, 6) STEP(13, 4) STEP(14, 2) STEP(15, 0)
#undef STEP

    // C/D: col j = jt*16 + (lane&15); row-in-chunk = (lane>>4)*4 + i.
    #pragma unroll
    for (int jt = 0; jt < 4; ++jt)
        #pragma unroll
        for (int i = 0; i < 4; ++i)
            dst[(size_t)(row0 + lhi * 4 + i) * kBD + jt * 16 + l15] = acc[jt][i] + bias[jt];
}

// Pass 2: S[b,j] = sum_rows kp[row,j] * vp[row,j].  512 blocks x 64 rows.
__global__ __launch_bounds__(256)
void lbm_comb(const float* __restrict__ kp, const float* __restrict__ vp,
              float* __restrict__ S)
{
    const int t  = threadIdx.x;
    const int j  = t & 63, rg = t >> 6;
    const int r0 = blockIdx.x * 64;
    float acc = 0.f;
    #pragma unroll
    for (int r = 0; r < 16; ++r) {
        size_t row = (size_t)(r0 + rg * 16 + r) * kBD;
        acc += kp[row + j] * vp[row + j];
    }
    __shared__ float red[4][kBD];
    red[rg][j] = acc;
    __syncthreads();
    if (t < kBD) {
        float s = red[0][t] + red[1][t] + red[2][t] + red[3][t];
        atomicAdd(&S[(r0 >> 12) * kBD + t], s);
    }
}

// Fallback bind (R11, verified): used when ws_size can't hold kp/vp.
__global__ __launch_bounds__(512, 2)
void lbm_bind(const float* __restrict__ keys, const float* __restrict__ values,
              const __bf16* __restrict__ wsk, const __bf16* __restrict__ wsv,
              const float* __restrict__ bbk,  const float* __restrict__ bbv,
              float* __restrict__ S)
{
    __shared__ __bf16 ldsW[2][kBD * kD];

    const int tid = threadIdx.x;
    const int w   = tid >> 6;
    const int ln  = tid & 63;
    const int l15 = ln & 15;
    const int lhi = ln >> 4;
    const int sw7 = l15 & 7;

    const int bid  = blockIdx.x;
    const int swzb = (bid & 7) * 32 + (bid >> 3);
    const int blockRow0 = swzb * 128;
    const int row0 = blockRow0 + w * 16;

    const float* kbase = keys   + (size_t)(row0 + l15) * kD + lhi * 8;
    const float* vbase = values + (size_t)(row0 + l15) * kD + lhi * 8;

    f32x4 ka[4], kb2[4], va[4], vb2[4];
    GLD2X(ka[0], kb2[0], kbase,   0) GLD2X(va[0], vb2[0], vbase,   0)
    GLD2X(ka[1], kb2[1], kbase, 128) GLD2X(va[1], vb2[1], vbase, 128)
    GLD2X(ka[2], kb2[2], kbase, 256) GLD2X(va[2], vb2[2], vbase, 256)
    GLD2X(ka[3], kb2[3], kbase, 384) GLD2X(va[3], vb2[3], vbase, 384)

    #pragma unroll
    for (int i = 0; i < 8; ++i) {
        int G = i * 512 + tid;
        int j = G >> 6, c = G & 63;
        int dst = j * kD + ((c ^ (j & 7)) << 3);
        *(bf16x8*)&ldsW[0][dst] = *(const bf16x8*)(wsk + G * 8);
        *(bf16x8*)&ldsW[1][dst] = *(const bf16x8*)(wsv + G * 8);
    }

    float bk[4], bv[4];
    #pragma unroll
    for (int jt = 0; jt < 4; ++jt) {
        bk[jt] = bbk[jt * 16 + l15];
        bv[jt] = bbv[jt * 16 + l15];
    }

    __syncthreads();

    f32x4 kacc[4], vacc[4];
    #pragma unroll
    for (int jt = 0; jt < 4; ++jt) {
        kacc[jt][0]=0.f; kacc[jt][1]=0.f; kacc[jt][2]=0.f; kacc[jt][3]=0.f;
        vacc[jt][0]=0.f; vacc[jt][1]=0.f; vacc[jt][2]=0.f; vacc[jt][3]=0.f;
    }

#define STEP(s_, n_)                                                          \
    {                                                                         \
        WAITN4(n_, ka[(s_) & 3], kb2[(s_) & 3], va[(s_) & 3], vb2[(s_) & 3])  \
        bf16x8 ak_ = cvt8v(ka[(s_) & 3], kb2[(s_) & 3]);                      \
        bf16x8 av_ = cvt8v(va[(s_) & 3], vb2[(s_) & 3]);                      \
        if ((s_) + 4 < 16) {                                                  \
            GLD2X(ka[(s_) & 3], kb2[(s_) & 3], kbase, ((s_) + 4) * 128)       \
            GLD2X(va[(s_) & 3], vb2[(s_) & 3], vbase, ((s_) + 4) * 128)       \
        }                                                                     \
        const int go_ = (((s_) * 4 + lhi) ^ sw7) << 3;                        \
        _Pragma("unroll")                                                     \
        for (int jt = 0; jt < 4; ++jt) {                                      \
            bf16x8 fk_ = *(const bf16x8*)&ldsW[0][(jt * 16 + l15) * kD + go_];\
            bf16x8 fv_ = *(const bf16x8*)&ldsW[1][(jt * 16 + l15) * kD + go_];\
            kacc[jt] = __builtin_amdgcn_mfma_f32_16x16x32_bf16(ak_, fk_, kacc[jt], 0, 0, 0); \
            vacc[jt] = __builtin_amdgcn_mfma_f32_16x16x32_bf16(av_, fv_, vacc[jt], 0, 0, 0); \
        }                                                                     \
    }

    STEP(0, 12)  STEP(1, 12)  STEP(2, 12)  STEP(3, 12)
    STEP(4, 12)  STEP(5, 12)  STEP(6, 12)  STEP(7, 12)
    STEP(8, 12)  STEP(9, 12)  STEP(10, 12) STEP(11, 12)
    STEP(12, 12) STEP(13, 8)  STEP(14, 4)  STEP(15, 0)
#undef STEP

    #pragma unroll
    for (int jt = 0; jt < 4; ++jt) {
        float sreg = 0.0f;
        #pragma unroll
        for (int i = 0; i < 4; ++i)
            sreg += (kacc[jt][i] + bk[jt]) * (vacc[jt][i] + bv[jt]);
        sreg += __shfl_xor(sreg, 16);
        sreg += __shfl_xor(sreg, 32);
        if (lhi == 0) {
            int bidx = blockRow0 >> 12;
            atomicAdd(&S[bidx * kBD + jt * 16 + l15], sreg);
        }
    }
}

// Fused tail: 64 blocks; each block redundantly computes S->Bsum->ms->ext->LN
// for its batch b (tiny), then produces its 64-wide slice of out = normed.Wo^T + bo.
__global__ __launch_bounds__(256)
void lbm_tail(const float* __restrict__ S,    const float* __restrict__ query,
              const float* __restrict__ Wbc,  const float* __restrict__ bbc,
              const float* __restrict__ Wuq,  const float* __restrict__ buq,
              const float* __restrict__ Wue,  const float* __restrict__ bue,
              const float* __restrict__ ln_g, const float* __restrict__ ln_b,
              const float* __restrict__ Wo,   const float* __restrict__ bo,
              float* __restrict__ out)
{
    const int b = blockIdx.x >> 3;
    const int s = blockIdx.x & 7;          // 64-wide output slice
    const int t = threadIdx.x;

    __shared__ float shS[kBD];
    __shared__ float shB[kD];
    __shared__ float shMs[kBD];
    __shared__ float shN[kD];
    __shared__ float redT[4][kBD];
    __shared__ float redQ[4][kBD];
    __shared__ float redLN[8];
    __shared__ float s_mu, s_rs;

    if (t < kBD) shS[t] = S[b * kBD + t];
    __syncthreads();

    // Bsum[d] = sum_j S[j]*Wbc[d,j] + n*bbc[d]
    for (int d = t; d < kD; d += 256) {
        const float4* wr = (const float4*)(Wbc + d * kBD);
        float acc = 0.f;
        #pragma unroll
        for (int q4 = 0; q4 < 16; ++q4) {
            float4 w = wr[q4];
            acc += w.x * shS[q4*4+0] + w.y * shS[q4*4+1]
                 + w.z * shS[q4*4+2] + w.w * shS[q4*4+3];
        }
        shB[d] = acc + (float)kN * bbc[d];
    }
    __syncthreads();

    // t[jj] = Bsum.Wuq[jj,:] + n*buq ; q[jj] = query.Wuq[jj,:] + buq ; ms = q*t
    {
        const int jj = t & 63, qq = t >> 6;
        const float4* wr = (const float4*)(Wuq + jj * kD + qq * 128);
        const float4* qr = (const float4*)(query + b * kD + qq * 128);
        const float4* br = (const float4*)(shB + qq * 128);
        float at = 0.f, aq = 0.f;
        #pragma unroll
        for (int i = 0; i < 32; ++i) {
            float4 w = wr[i]; float4 bb = br[i]; float4 qv = qr[i];
            at += w.x*bb.x + w.y*bb.y + w.z*bb.z + w.w*bb.w;
            aq += w.x*qv.x + w.y*qv.y + w.z*qv.z + w.w*qv.w;
        }
        redT[qq][jj] = at; redQ[qq][jj] = aq;
    }
    __syncthreads();
    if (t < kBD) {
        float tv = redT[0][t] + redT[1][t] + redT[2][t] + redT[3][t] + (float)kN * buq[t];
        float qv = redQ[0][t] + redQ[1][t] + redQ[2][t] + redQ[3][t] + buq[t];
        shMs[t] = tv * qv;
    }
    __syncthreads();

    // ext[d] -> ret -> LN stats
    float lsum = 0.f, lsq = 0.f;
    for (int d = t; d < kD; d += 256) {
        const float4* wr = (const float4*)(Wue + d * kBD);
        float acc = 0.f;
        #pragma unroll
        for (int q4 = 0; q4 < 16; ++q4) {
            float4 w = wr[q4];
            acc += w.x * shMs[q4*4+0] + w.y * shMs[q4*4+1]
                 + w.z * shMs[q4*4+2] + w.w * shMs[q4*4+3];
        }
        float ret = (acc + (float)kN * bue[d]) * (1.0f / 64.0f);
        shN[d] = ret;
        lsum += ret; lsq += ret * ret;
    }
    #pragma unroll
    for (int m = 1; m < 64; m <<= 1) {
        lsum += __shfl_xor(lsum, m);
        lsq  += __shfl_xor(lsq, m);
    }
    if ((t & 63) == 0) { redLN[t >> 6] = lsum; redLN[4 + (t >> 6)] = lsq; }
    __syncthreads();
    if (t == 0) {
        float s0 = redLN[0] + redLN[1] + redLN[2] + redLN[3];
        float s1 = redLN[4] + redLN[5] + redLN[6] + redLN[7];
        float mu = s0 / (float)kD;
        float var = s1 / (float)kD - mu * mu;
        s_mu = mu;
        s_rs = rsqrtf(var + 1e-5f);
    }
    __syncthreads();
    {
        float mu = s_mu, rs = s_rs;
        for (int d = t; d < kD; d += 256)
            shN[d] = (shN[d] - mu) * rs * ln_g[d] + ln_b[d];
    }
    __syncthreads();

    // out slice: d = s*64 + t/4, quarter q = t&3 over the 512-dot
    {
        const int d = s * 64 + (t >> 2);
        const int q = t & 3;
        const float4* wr = (const float4*)(Wo + d * kD + q * 128);
        const float4* nr = (const float4*)(shN + q * 128);
        float acc = 0.f;
        #pragma unroll
        for (int i = 0; i < 32; ++i) {
            float4 w = wr[i]; float4 nv = nr[i];
            acc += w.x*nv.x + w.y*nv.y + w.z*nv.z + w.w*nv.w;
        }
        acc += __shfl_xor(acc, 1);
        acc += __shfl_xor(acc, 2);
        if (q == 0) out[b * kD + d] = acc + bo[d];
    }
}

extern "C" void kernel_launch(void* const* d_in, const int* in_sizes, int n_in,
                              void* d_out, int out_size, void* d_ws, size_t ws_size,
                              hipStream_t stream) {
    const float* keys   = (const float*)d_in[0];
    const float* values = (const float*)d_in[1];
    const float* query  = (const float*)d_in[2];
    const float* Wbk    = (const float*)d_in[3];
    const float* bbk    = (const float*)d_in[4];
    const float* Wbv    = (const float*)d_in[5];
    const float* bbv    = (const float*)d_in[6];
    const float* Wbc    = (const float*)d_in[7];
    const float* bbc    = (const float*)d_in[8];
    const float* Wuq    = (const float*)d_in[9];
    const float* buq    = (const float*)d_in[10];
    const float* Wue    = (const float*)d_in[11];
    const float* bue    = (const float*)d_in[12];
    const float* ln_g   = (const float*)d_in[13];
    const float* ln_b   = (const float*)d_in[14];
    const float* Wo     = (const float*)d_in[15];
    const float* bo     = (const float*)d_in[16];

    // ws layout: S (2 KB) | wsk (64 KB) | wsv (64 KB) | kp (8.4 MB) | vp (8.4 MB)
    float*  Sacc = (float*)d_ws;
    __bf16* wsk  = (__bf16*)((char*)d_ws + 2048);
    __bf16* wsv  = wsk + kBD * kD;
    float*  kp   = (float*)((char*)d_ws + 2048 + 2 * kBD * kD * sizeof(__bf16));
    float*  vp   = kp + (size_t)kB * kN * kBD;
    float*  out  = (float*)d_out;

    const size_t need = 2048 + 2 * (size_t)kBD * kD * sizeof(__bf16)
                      + 2 * (size_t)kB * kN * kBD * sizeof(float);

    lbm_prep<<<dim3(33), dim3(256), 0, stream>>>(Wbk, Wbv, wsk, wsv, Sacc);

    if (ws_size >= need) {
        lbm_proj<<<dim3(512), dim3(512), 0, stream>>>(keys, values, wsk, wsv,
                                                      bbk, bbv, kp, vp);
        lbm_comb<<<dim3(512), dim3(256), 0, stream>>>(kp, vp, Sacc);
    } else {
        lbm_bind<<<dim3(256), dim3(512), 0, stream>>>(keys, values, wsk, wsv,
                                                      bbk, bbv, Sacc);
    }
    lbm_tail<<<dim3(kB * 8), dim3(256), 0, stream>>>(Sacc, query, Wbc, bbc, Wuq, buq,
                                                     Wue, bue, ln_g, ln_b, Wo, bo, out);
}